// Round 4
// baseline (215.166 us; speedup 1.0000x reference)
//
#include <hip/hip_runtime.h>
#include <math.h>

#define T_  4
#define B_  16
#define C_  384
#define HW_ 256
#define E_  8

typedef __attribute__((ext_vector_type(8))) __bf16 bf16x8;
typedef __attribute__((ext_vector_type(4))) float f32x4;

union FragU { uint4 u; bf16x8 v; };

// taus = jnp.linspace(1.5, 4.0, 8) in fp32, endpoint exact
__device__ __forceinline__ float tau_of(int e) {
    if (e == 7) return 4.0f;
    const float delta = 2.5f / 7.0f;
    return __fadd_rn(1.5f, __fmul_rn((float)e, delta));
}

// bits of m (8 spikes) -> bf16x8 {0,1} fragment
__device__ __forceinline__ FragU expand_mask(unsigned m) {
    FragU f;
    f.u.x = ((m & 1u)   ? 0x3F80u : 0u) | ((m & 2u)   ? 0x3F800000u : 0u);
    f.u.y = ((m & 4u)   ? 0x3F80u : 0u) | ((m & 8u)   ? 0x3F800000u : 0u);
    f.u.z = ((m & 16u)  ? 0x3F80u : 0u) | ((m & 32u)  ? 0x3F800000u : 0u);
    f.u.w = ((m & 64u)  ? 0x3F80u : 0u) | ((m & 128u) ? 0x3F800000u : 0u);
    return f;
}

// ---------------- k_prep: fused weight-split + router LIF (unchanged) -------
__global__ __launch_bounds__(256) void k_prep(const float* __restrict__ x,
        const float* __restrict__ W1, const float* __restrict__ W2,
        unsigned short* __restrict__ Whif, unsigned short* __restrict__ Wlof,
        float* __restrict__ m) {
    if (blockIdx.x < 1152) {
        int tid = blockIdx.x * 256 + threadIdx.x;    // 294912 total
        int l = tid & 63;
        int f = tid >> 6;                            // 0..4607
        int osub = f % 24;
        int ksub = (f / 24) % 12;
        int cv = (f / 288) & 1;
        int e = f / 576;
        const float* Wsrc = (cv == 0 ? W1 : W2) + (size_t)e * C_ * C_;
        int o = osub * 16 + (l & 15);
        int c0 = ksub * 32 + (l >> 4) * 8;
        const float* src = Wsrc + (size_t)o * C_ + c0;
        unsigned hw[8], lw[8];
#pragma unroll
        for (int j = 0; j < 8; ++j) {
            float w = src[j];
            unsigned u = __float_as_uint(w);
            unsigned hi = (u + 0x7FFFu + ((u >> 16) & 1u)) >> 16;
            float hf = __uint_as_float(hi << 16);
            float res = __fsub_rn(w, hf);
            unsigned ru = __float_as_uint(res);
            unsigned lo = (ru + 0x7FFFu + ((ru >> 16) & 1u)) >> 16;
            hw[j] = hi & 0xFFFFu;
            lw[j] = lo & 0xFFFFu;
        }
        size_t dst = (size_t)f * 512 + (size_t)l * 8;
        uint4 hv = make_uint4(hw[0] | (hw[1] << 16), hw[2] | (hw[3] << 16),
                              hw[4] | (hw[5] << 16), hw[6] | (hw[7] << 16));
        uint4 lv = make_uint4(lw[0] | (lw[1] << 16), lw[2] | (lw[3] << 16),
                              lw[4] | (lw[5] << 16), lw[6] | (lw[7] << 16));
        *reinterpret_cast<uint4*>(Whif + dst) = hv;
        *reinterpret_cast<uint4*>(Wlof + dst) = lv;
    } else {
        int bc = blockIdx.x - 1152;
        int b = bc / C_, c = bc % C_;
        int p = threadIdx.x;
        int wv = threadIdx.x >> 6;
        __shared__ int cnt[T_][4];
        float v = 0.0f;
#pragma unroll
        for (int t = 0; t < T_; ++t) {
            float xv = x[((t * B_ + b) * C_ + c) * HW_ + p];
            v = __fadd_rn(v, __fdiv_rn(__fsub_rn(xv, v), 2.0f));
            bool s = (__fsub_rn(v, 1.0f) >= 0.0f);
            if (s) v = 0.0f;
            unsigned long long mask = __ballot(s);
            if ((threadIdx.x & 63) == 0) cnt[t][wv] = (int)__popcll(mask);
        }
        __syncthreads();
        if (threadIdx.x < T_) {
            int t = threadIdx.x;
            int tot = cnt[t][0] + cnt[t][1] + cnt[t][2] + cnt[t][3];
            m[(t * B_ + b) * C_ + c] = (float)tot * 0.00390625f;
        }
    }
}

// ---------------- conv core v2: B-frags via ds_read_b128 from LDS -----------
// sf holds pre-expanded bf16 {0,1} fragments: frag(ksub,t) at ksub*4096+t*1024,
// lane l owns bytes [l*16, l*16+16) => elements c = ksub*32+(l>>4)*8+j, col=l&15.
// acc is C-in/C-out (may be pre-initialized by the caller).
__device__ __forceinline__ void conv_mfma2(const unsigned short* __restrict__ Whif,
                                           const unsigned short* __restrict__ Wlof,
                                           unsigned base,
                                           const unsigned char* __restrict__ sf,
                                           f32x4 (&acc)[3][4],
                                           int wv, int lane) {
    const unsigned lane8 = (unsigned)lane * 8u;
    const unsigned wbase = base + (unsigned)(wv * 3) * 512u + lane8;
    const unsigned char* fp = sf + lane * 16;
    FragU c0f, c1f, c2f, n0f, n1f, n2f, bf[T_];
    c0f.u = *reinterpret_cast<const uint4*>(Wlof + wbase);
    c1f.u = *reinterpret_cast<const uint4*>(Wlof + wbase + 512u);
    c2f.u = *reinterpret_cast<const uint4*>(Wlof + wbase + 1024u);
#pragma unroll 1
    for (int ksub = 0; ksub < 12; ++ksub) {
        unsigned fo = wbase + (unsigned)ksub * 24u * 512u;
        const unsigned char* fk = fp + ksub * 4096;
#pragma unroll
        for (int t = 0; t < T_; ++t)
            bf[t].u = *reinterpret_cast<const uint4*>(fk + t * 1024);
        n0f.u = *reinterpret_cast<const uint4*>(Whif + fo);
        n1f.u = *reinterpret_cast<const uint4*>(Whif + fo + 512u);
        n2f.u = *reinterpret_cast<const uint4*>(Whif + fo + 1024u);
#pragma unroll
        for (int t = 0; t < T_; ++t) {
            acc[0][t] = __builtin_amdgcn_mfma_f32_16x16x32_bf16(c0f.v, bf[t].v, acc[0][t], 0, 0, 0);
            acc[1][t] = __builtin_amdgcn_mfma_f32_16x16x32_bf16(c1f.v, bf[t].v, acc[1][t], 0, 0, 0);
            acc[2][t] = __builtin_amdgcn_mfma_f32_16x16x32_bf16(c2f.v, bf[t].v, acc[2][t], 0, 0, 0);
        }
        if (ksub < 11) {
            unsigned fn = fo + 24u * 512u;
            c0f.u = *reinterpret_cast<const uint4*>(Wlof + fn);
            c1f.u = *reinterpret_cast<const uint4*>(Wlof + fn + 512u);
            c2f.u = *reinterpret_cast<const uint4*>(Wlof + fn + 1024u);
        }
#pragma unroll
        for (int t = 0; t < T_; ++t) {
            acc[0][t] = __builtin_amdgcn_mfma_f32_16x16x32_bf16(n0f.v, bf[t].v, acc[0][t], 0, 0, 0);
            acc[1][t] = __builtin_amdgcn_mfma_f32_16x16x32_bf16(n1f.v, bf[t].v, acc[1][t], 0, 0, 0);
            acc[2][t] = __builtin_amdgcn_mfma_f32_16x16x32_bf16(n2f.v, bf[t].v, acc[2][t], 0, 0, 0);
        }
    }
}

// ---------------- k_expert v3: 512-thread rank-per-block --------------------
// grid 512 = (b x ptile x rank), 512 threads (8 waves). Each block computes ONE
// of the top-2 experts for its (b,ptile) tile; the two rank-blocks combine via
// atomicAdd into a zeroed output (2 commutative fadds -> bit-exact sum).
// 512-thread shape restores the compiler's ~120-VGPR allocation (1024-thread
// variants were hard-clamped to 64 VGPRs -> 40 regs spilled -> 135 MB scratch).
__global__ __launch_bounds__(512, 4) void k_expert(
        const float* __restrict__ x, const float* __restrict__ m,
        const float* __restrict__ rW, const float* __restrict__ rb,
        const float* __restrict__ rbs, const float* __restrict__ rbb,
        const unsigned short* __restrict__ Whif, const unsigned short* __restrict__ Wlof,
        const float* __restrict__ b1, const float* __restrict__ s1sc, const float* __restrict__ s1bi,
        const float* __restrict__ b2, const float* __restrict__ s2sc, const float* __restrict__ s2bi,
        float* __restrict__ out) {
    int blk = blockIdx.x;
    int rank = blk & 1;
    int b = (blk >> 1) & 15;
    int ptile = blk >> 5;

    __shared__ __align__(16) unsigned char sfrag[49152];   // 48 KB B-fragments
    __shared__ float bns[7 * C_];    // [A1,B1,BB1,A2,B2,BB2,rA2][o] (own rank)
    __shared__ float lg[E_];
    __shared__ float wsl[2];
    __shared__ int esl[2];

    int tid = threadIdx.x;
    int wv = tid >> 6;            // wave 0..7
    int lane = tid & 63;
    int q = lane >> 4;
    int pl = lane & 15;
    int p = ptile * 16 + pl;
    float denom = sqrtf(__fadd_rn(1.0f, 1e-5f));

    // ---- inline route (wave 0), identical arithmetic to previous version
    if (tid < 64) {
        int combo = tid & 31, half = tid >> 5;
        int e = combo >> 2, t = combo & 3;
        float dot = 0.0f;
        int c0 = half * 192;
        for (int c = 0; c < 192; ++c)
            dot = fmaf(rW[e * C_ + c0 + c], m[(t * B_ + b) * C_ + c0 + c], dot);
        dot += __shfl_down(dot, 32);
        float Ar = __fdiv_rn(rbs[e], denom);
        float lt = __fadd_rn(__fmul_rn(__fadd_rn(dot, rb[e]), Ar), rbb[e]);
        lt = __fadd_rn(lt, __shfl_xor(lt, 1));
        lt = __fadd_rn(lt, __shfl_xor(lt, 2));
        if (half == 0 && t == 0) lg[e] = __fmul_rn(lt, 0.25f);
    }
    __syncthreads();
    if (tid == 0) {
        float pr[E_];
        float mx = lg[0];
        for (int i = 1; i < E_; ++i) mx = fmaxf(mx, lg[i]);
        float s = 0.0f;
        for (int i = 0; i < E_; ++i) { pr[i] = expf(__fsub_rn(lg[i], mx)); s = __fadd_rn(s, pr[i]); }
        for (int i = 0; i < E_; ++i) pr[i] = __fdiv_rn(pr[i], s);
        int i0 = 0;
        for (int i = 1; i < E_; ++i) if (pr[i] > pr[i0]) i0 = i;
        int i1 = (i0 == 0) ? 1 : 0;
        for (int i = 0; i < E_; ++i) if (i != i0 && pr[i] > pr[i1]) i1 = i;
        float s2 = __fadd_rn(pr[i0], pr[i1]);
        wsl[0] = __fdiv_rn(pr[i0], s2);
        wsl[1] = __fdiv_rn(pr[i1], s2);
        esl[0] = i0;
        esl[1] = i1;
    }
    __syncthreads();

    int er = esl[rank];
    float wr = wsl[rank];
    float taur = tau_of(er);

    // ---- BN staging (own rank)
    if (tid < C_) {
        float a1 = __fdiv_rn(s1sc[er * C_ + tid], denom);
        float a2 = __fdiv_rn(s2sc[er * C_ + tid], denom);
        bns[0 * C_ + tid] = a1;
        bns[1 * C_ + tid] = b1[er * C_ + tid];
        bns[2 * C_ + tid] = s1bi[er * C_ + tid];
        bns[3 * C_ + tid] = a2;
        bns[4 * C_ + tid] = b2[er * C_ + tid];
        bns[5 * C_ + tid] = s2bi[er * C_ + tid];
        bns[6 * C_ + tid] = __fdiv_rn(1.0f, a2);   // rA2 (acc-fold)
    }

    // ---- LIF1 (own tau): write expanded bf16 frags straight to LDS
#pragma unroll 1
    for (int task = tid; task < 48 * 16; task += 512) {
        int cb = task >> 4;          // c-group of 8: 0..47
        int tpl = task & 15;
        int tp = ptile * 16 + tpl;
        unsigned char* dst = sfrag + (cb >> 2) * 4096 + (((cb & 3) * 16 + tpl) * 16);
        float v[8];
#pragma unroll
        for (int j = 0; j < 8; ++j) v[j] = 0.0f;
#pragma unroll
        for (int t = 0; t < T_; ++t) {
            int gbase = ((t * B_ + b) * C_ + cb * 8) * HW_ + tp;
            unsigned d0 = 0, d1 = 0, d2 = 0, d3 = 0;
#pragma unroll
            for (int j = 0; j < 8; ++j) {
                float xv = x[gbase + j * HW_];
                v[j] = __fadd_rn(v[j], __fdiv_rn(__fsub_rn(xv, v[j]), taur));
                bool s = (__fsub_rn(v[j], 1.0f) >= 0.0f);
                if (s) v[j] = 0.0f;
                unsigned bitv = s ? ((j & 1) ? 0x3F800000u : 0x3F80u) : 0u;
                if (j < 2) d0 |= bitv;
                else if (j < 4) d1 |= bitv;
                else if (j < 6) d2 |= bitv;
                else d3 |= bitv;
            }
            *reinterpret_cast<uint4*>(dst + t * 1024) = make_uint4(d0, d1, d2, d3);
        }
    }
    __syncthreads();

    // ---- conv1
    f32x4 acc[3][T_];
#pragma unroll
    for (int os = 0; os < 3; ++os)
#pragma unroll
        for (int t = 0; t < T_; ++t) acc[os][t] = (f32x4)0.0f;
    unsigned base1 = (unsigned)(er * 2) * 12u * 24u * 512u;
    conv_mfma2(Whif, Wlof, base1, sfrag, acc, wv, lane);

    // ---- epi1: h = x + bn1(y); LIF2 bits; acc := h * rA2 (fold into conv2 C-in)
    unsigned pk[3];
#pragma unroll
    for (int os = 0; os < 3; ++os) {
        float v2s[4] = {0.f, 0.f, 0.f, 0.f};
        unsigned pkos = 0;
#pragma unroll
        for (int t = 0; t < T_; ++t) {
            unsigned nb = 0;
#pragma unroll
            for (int r = 0; r < 4; ++r) {
                int o = wv * 48 + os * 16 + q * 4 + r;
                int gi = ((t * B_ + b) * C_ + o) * HW_ + p;
                float y = acc[os][t][r];
                float h = __fadd_rn(x[gi],
                    __fadd_rn(__fmul_rn(__fadd_rn(y, bns[1 * C_ + o]), bns[0 * C_ + o]),
                              bns[2 * C_ + o]));
                v2s[r] = __fadd_rn(v2s[r], __fdiv_rn(__fsub_rn(h, v2s[r]), taur));
                if (__fsub_rn(v2s[r], 1.0f) >= 0.0f) { nb |= (1u << r); v2s[r] = 0.f; }
                acc[os][t][r] = __fmul_rn(h, bns[6 * C_ + o]);
            }
            unsigned nb_hi = (unsigned)__shfl_down((int)nb, 16);
            pkos |= ((nb | (nb_hi << 4)) & 0xFFu) << (8 * t);
        }
        pk[os] = pkos;
    }
    __syncthreads();   // all conv1 reads of sfrag complete before overwrite

    // ---- write s2 frags (even-q threads own full bytes)
    if ((q & 1) == 0) {
#pragma unroll
        for (int os = 0; os < 3; ++os) {
            int g = wv * 6 + os * 2 + (q >> 1);      // c-group of 8 for conv2 B
            unsigned char* dst = sfrag + (g >> 2) * 4096 + (((g & 3) * 16 + pl) * 16);
#pragma unroll
            for (int t = 0; t < T_; ++t) {
                FragU f = expand_mask((pk[os] >> (8 * t)) & 0xFFu);
                *reinterpret_cast<uint4*>(dst + t * 1024) = f.u;
            }
        }
    }
    __syncthreads();

    // ---- conv2 (acc carries folded residual)
    unsigned base2 = (unsigned)(er * 2 + 1) * 12u * 24u * 512u;
    conv_mfma2(Whif, Wlof, base2, sfrag, acc, wv, lane);

    // ---- epi2: val = (acc + B2)*A2 + BB2 (= bn2(y2) + h); combine via atomics
#pragma unroll
    for (int os = 0; os < 3; ++os)
#pragma unroll
        for (int t = 0; t < T_; ++t)
#pragma unroll
            for (int r = 0; r < 4; ++r) {
                int o = wv * 48 + os * 16 + q * 4 + r;
                int gi = ((t * B_ + b) * C_ + o) * HW_ + p;
                float y = acc[os][t][r];
                float val = __fadd_rn(__fmul_rn(__fadd_rn(y, bns[4 * C_ + o]),
                                                bns[3 * C_ + o]),
                                      bns[5 * C_ + o]);
                atomicAdd(out + gi, __fmul_rn(wr, val));
            }
}

extern "C" void kernel_launch(void* const* d_in, const int* in_sizes, int n_in,
                              void* d_out, int out_size, void* d_ws, size_t ws_size,
                              hipStream_t stream) {
    const float* x    = (const float*)d_in[0];
    const float* rW   = (const float*)d_in[1];
    const float* rb   = (const float*)d_in[2];
    const float* rbs  = (const float*)d_in[3];
    const float* rbb  = (const float*)d_in[4];
    const float* W1   = (const float*)d_in[5];
    const float* b1   = (const float*)d_in[6];
    const float* s1sc = (const float*)d_in[7];
    const float* s1bi = (const float*)d_in[8];
    const float* W2   = (const float*)d_in[9];
    const float* b2   = (const float*)d_in[10];
    const float* s2sc = (const float*)d_in[11];
    const float* s2bi = (const float*)d_in[12];
    float* out = (float*)d_out;

    // ws layout: Whif (4718592 B) | Wlof (4718592 B) | m (24576 floats)
    unsigned short* Whif = (unsigned short*)d_ws;
    unsigned short* Wlof = Whif + 2359296;
    float* m = (float*)((char*)d_ws + 9437184);

    hipLaunchKernelGGL(k_prep, dim3(1152 + B_ * C_), dim3(256), 0, stream,
                       x, W1, W2, Whif, Wlof, m);
    hipMemsetAsync(d_out, 0, out_size, stream);   // atomic-combine needs zeroed out
    hipLaunchKernelGGL(k_expert, dim3(512), dim3(512), 0, stream,
                       x, m, rW, rb, rbs, rbb, Whif, Wlof,
                       b1, s1sc, s1bi, b2, s2sc, s2bi, out);
}

// Round 5
// 198.268 us; speedup vs baseline: 1.0852x; 1.0852x over previous
//
#include <hip/hip_runtime.h>
#include <math.h>

#define T_  4
#define B_  16
#define C_  384
#define HW_ 256
#define E_  8

typedef __attribute__((ext_vector_type(8))) __bf16 bf16x8;
typedef __attribute__((ext_vector_type(4))) float f32x4;

union FragU { uint4 u; bf16x8 v; };

// taus = jnp.linspace(1.5, 4.0, 8) in fp32, endpoint exact
__device__ __forceinline__ float tau_of(int e) {
    if (e == 7) return 4.0f;
    const float delta = 2.5f / 7.0f;
    return __fadd_rn(1.5f, __fmul_rn((float)e, delta));
}

// bits of m (8 spikes) -> bf16x8 {0,1} fragment
__device__ __forceinline__ FragU expand_mask(unsigned m) {
    FragU f;
    f.u.x = ((m & 1u)   ? 0x3F80u : 0u) | ((m & 2u)   ? 0x3F800000u : 0u);
    f.u.y = ((m & 4u)   ? 0x3F80u : 0u) | ((m & 8u)   ? 0x3F800000u : 0u);
    f.u.z = ((m & 16u)  ? 0x3F80u : 0u) | ((m & 32u)  ? 0x3F800000u : 0u);
    f.u.w = ((m & 64u)  ? 0x3F80u : 0u) | ((m & 128u) ? 0x3F800000u : 0u);
    return f;
}

// ---------------- k_prep: fused weight-split + router LIF (unchanged) -------
__global__ __launch_bounds__(256) void k_prep(const float* __restrict__ x,
        const float* __restrict__ W1, const float* __restrict__ W2,
        unsigned short* __restrict__ Whif, unsigned short* __restrict__ Wlof,
        float* __restrict__ m) {
    if (blockIdx.x < 1152) {
        int tid = blockIdx.x * 256 + threadIdx.x;    // 294912 total
        int l = tid & 63;
        int f = tid >> 6;                            // 0..4607
        int osub = f % 24;
        int ksub = (f / 24) % 12;
        int cv = (f / 288) & 1;
        int e = f / 576;
        const float* Wsrc = (cv == 0 ? W1 : W2) + (size_t)e * C_ * C_;
        int o = osub * 16 + (l & 15);
        int c0 = ksub * 32 + (l >> 4) * 8;
        const float* src = Wsrc + (size_t)o * C_ + c0;
        unsigned hw[8], lw[8];
#pragma unroll
        for (int j = 0; j < 8; ++j) {
            float w = src[j];
            unsigned u = __float_as_uint(w);
            unsigned hi = (u + 0x7FFFu + ((u >> 16) & 1u)) >> 16;
            float hf = __uint_as_float(hi << 16);
            float res = __fsub_rn(w, hf);
            unsigned ru = __float_as_uint(res);
            unsigned lo = (ru + 0x7FFFu + ((ru >> 16) & 1u)) >> 16;
            hw[j] = hi & 0xFFFFu;
            lw[j] = lo & 0xFFFFu;
        }
        size_t dst = (size_t)f * 512 + (size_t)l * 8;
        uint4 hv = make_uint4(hw[0] | (hw[1] << 16), hw[2] | (hw[3] << 16),
                              hw[4] | (hw[5] << 16), hw[6] | (hw[7] << 16));
        uint4 lv = make_uint4(lw[0] | (lw[1] << 16), lw[2] | (lw[3] << 16),
                              lw[4] | (lw[5] << 16), lw[6] | (lw[7] << 16));
        *reinterpret_cast<uint4*>(Whif + dst) = hv;
        *reinterpret_cast<uint4*>(Wlof + dst) = lv;
    } else {
        int bc = blockIdx.x - 1152;
        int b = bc / C_, c = bc % C_;
        int p = threadIdx.x;
        int wv = threadIdx.x >> 6;
        __shared__ int cnt[T_][4];
        float v = 0.0f;
#pragma unroll
        for (int t = 0; t < T_; ++t) {
            float xv = x[((t * B_ + b) * C_ + c) * HW_ + p];
            v = __fadd_rn(v, __fdiv_rn(__fsub_rn(xv, v), 2.0f));
            bool s = (__fsub_rn(v, 1.0f) >= 0.0f);
            if (s) v = 0.0f;
            unsigned long long mask = __ballot(s);
            if ((threadIdx.x & 63) == 0) cnt[t][wv] = (int)__popcll(mask);
        }
        __syncthreads();
        if (threadIdx.x < T_) {
            int t = threadIdx.x;
            int tot = cnt[t][0] + cnt[t][1] + cnt[t][2] + cnt[t][3];
            m[(t * B_ + b) * C_ + c] = (float)tot * 0.00390625f;
        }
    }
}

// ---------------- conv core v2: B-frags via ds_read_b128 from LDS -----------
// sf holds pre-expanded bf16 {0,1} fragments: frag(ksub,t) at ksub*4096+t*1024,
// lane l owns bytes [l*16, l*16+16) => elements c = ksub*32+(l>>4)*8+j, col=l&15.
// acc is C-in/C-out (may be pre-initialized by the caller).
__device__ __forceinline__ void conv_mfma2(const unsigned short* __restrict__ Whif,
                                           const unsigned short* __restrict__ Wlof,
                                           unsigned base,
                                           const unsigned char* __restrict__ sf,
                                           f32x4 (&acc)[3][4],
                                           int wv, int lane) {
    const unsigned lane8 = (unsigned)lane * 8u;
    const unsigned wbase = base + (unsigned)(wv * 3) * 512u + lane8;
    const unsigned char* fp = sf + lane * 16;
    FragU c0f, c1f, c2f, n0f, n1f, n2f, bf[T_];
    c0f.u = *reinterpret_cast<const uint4*>(Wlof + wbase);
    c1f.u = *reinterpret_cast<const uint4*>(Wlof + wbase + 512u);
    c2f.u = *reinterpret_cast<const uint4*>(Wlof + wbase + 1024u);
#pragma unroll 1
    for (int ksub = 0; ksub < 12; ++ksub) {
        unsigned fo = wbase + (unsigned)ksub * 24u * 512u;
        const unsigned char* fk = fp + ksub * 4096;
#pragma unroll
        for (int t = 0; t < T_; ++t)
            bf[t].u = *reinterpret_cast<const uint4*>(fk + t * 1024);
        n0f.u = *reinterpret_cast<const uint4*>(Whif + fo);
        n1f.u = *reinterpret_cast<const uint4*>(Whif + fo + 512u);
        n2f.u = *reinterpret_cast<const uint4*>(Whif + fo + 1024u);
#pragma unroll
        for (int t = 0; t < T_; ++t) {
            acc[0][t] = __builtin_amdgcn_mfma_f32_16x16x32_bf16(c0f.v, bf[t].v, acc[0][t], 0, 0, 0);
            acc[1][t] = __builtin_amdgcn_mfma_f32_16x16x32_bf16(c1f.v, bf[t].v, acc[1][t], 0, 0, 0);
            acc[2][t] = __builtin_amdgcn_mfma_f32_16x16x32_bf16(c2f.v, bf[t].v, acc[2][t], 0, 0, 0);
        }
        if (ksub < 11) {
            unsigned fn = fo + 24u * 512u;
            c0f.u = *reinterpret_cast<const uint4*>(Wlof + fn);
            c1f.u = *reinterpret_cast<const uint4*>(Wlof + fn + 512u);
            c2f.u = *reinterpret_cast<const uint4*>(Wlof + fn + 1024u);
        }
#pragma unroll
        for (int t = 0; t < T_; ++t) {
            acc[0][t] = __builtin_amdgcn_mfma_f32_16x16x32_bf16(n0f.v, bf[t].v, acc[0][t], 0, 0, 0);
            acc[1][t] = __builtin_amdgcn_mfma_f32_16x16x32_bf16(n1f.v, bf[t].v, acc[1][t], 0, 0, 0);
            acc[2][t] = __builtin_amdgcn_mfma_f32_16x16x32_bf16(n2f.v, bf[t].v, acc[2][t], 0, 0, 0);
        }
    }
}

// ---------------- k_expert v3.1: 512-thread rank-per-block ------------------
// grid 512 = (b x ptile x rank), 512 threads (8 waves). Each block computes ONE
// of the top-2 experts for its (b,ptile) tile; the two rank-blocks combine via
// atomicAdd into a zeroed output (2 commutative fadds -> bit-exact sum).
// __launch_bounds__(512, 2): the ONLY launch config empirically giving a sane
// register allocation (120 VGPR, no spill). Args (512,4)/(1024,*) all clamped
// to 64 VGPR -> ~40 regs spilled -> 100+ MB scratch traffic (rounds 1-4).
__global__ __launch_bounds__(512, 2) void k_expert(
        const float* __restrict__ x, const float* __restrict__ m,
        const float* __restrict__ rW, const float* __restrict__ rb,
        const float* __restrict__ rbs, const float* __restrict__ rbb,
        const unsigned short* __restrict__ Whif, const unsigned short* __restrict__ Wlof,
        const float* __restrict__ b1, const float* __restrict__ s1sc, const float* __restrict__ s1bi,
        const float* __restrict__ b2, const float* __restrict__ s2sc, const float* __restrict__ s2bi,
        float* __restrict__ out) {
    int blk = blockIdx.x;
    int rank = blk & 1;
    int b = (blk >> 1) & 15;
    int ptile = blk >> 5;

    __shared__ __align__(16) unsigned char sfrag[49152];   // 48 KB B-fragments
    __shared__ float bns[7 * C_];    // [A1,B1,BB1,A2,B2,BB2,rA2][o] (own rank)
    __shared__ float lg[E_];
    __shared__ float wsl[2];
    __shared__ int esl[2];

    int tid = threadIdx.x;
    int wv = tid >> 6;            // wave 0..7
    int lane = tid & 63;
    int q = lane >> 4;
    int pl = lane & 15;
    int p = ptile * 16 + pl;
    float denom = sqrtf(__fadd_rn(1.0f, 1e-5f));

    // ---- inline route (wave 0), identical arithmetic to previous version
    if (tid < 64) {
        int combo = tid & 31, half = tid >> 5;
        int e = combo >> 2, t = combo & 3;
        float dot = 0.0f;
        int c0 = half * 192;
        for (int c = 0; c < 192; ++c)
            dot = fmaf(rW[e * C_ + c0 + c], m[(t * B_ + b) * C_ + c0 + c], dot);
        dot += __shfl_down(dot, 32);
        float Ar = __fdiv_rn(rbs[e], denom);
        float lt = __fadd_rn(__fmul_rn(__fadd_rn(dot, rb[e]), Ar), rbb[e]);
        lt = __fadd_rn(lt, __shfl_xor(lt, 1));
        lt = __fadd_rn(lt, __shfl_xor(lt, 2));
        if (half == 0 && t == 0) lg[e] = __fmul_rn(lt, 0.25f);
    }
    __syncthreads();
    if (tid == 0) {
        float pr[E_];
        float mx = lg[0];
        for (int i = 1; i < E_; ++i) mx = fmaxf(mx, lg[i]);
        float s = 0.0f;
        for (int i = 0; i < E_; ++i) { pr[i] = expf(__fsub_rn(lg[i], mx)); s = __fadd_rn(s, pr[i]); }
        for (int i = 0; i < E_; ++i) pr[i] = __fdiv_rn(pr[i], s);
        int i0 = 0;
        for (int i = 1; i < E_; ++i) if (pr[i] > pr[i0]) i0 = i;
        int i1 = (i0 == 0) ? 1 : 0;
        for (int i = 0; i < E_; ++i) if (i != i0 && pr[i] > pr[i1]) i1 = i;
        float s2 = __fadd_rn(pr[i0], pr[i1]);
        wsl[0] = __fdiv_rn(pr[i0], s2);
        wsl[1] = __fdiv_rn(pr[i1], s2);
        esl[0] = i0;
        esl[1] = i1;
    }
    __syncthreads();

    int er = esl[rank];
    float wr = wsl[rank];
    float taur = tau_of(er);

    // ---- BN staging (own rank)
    if (tid < C_) {
        float a1 = __fdiv_rn(s1sc[er * C_ + tid], denom);
        float a2 = __fdiv_rn(s2sc[er * C_ + tid], denom);
        bns[0 * C_ + tid] = a1;
        bns[1 * C_ + tid] = b1[er * C_ + tid];
        bns[2 * C_ + tid] = s1bi[er * C_ + tid];
        bns[3 * C_ + tid] = a2;
        bns[4 * C_ + tid] = b2[er * C_ + tid];
        bns[5 * C_ + tid] = s2bi[er * C_ + tid];
        bns[6 * C_ + tid] = __fdiv_rn(1.0f, a2);   // rA2 (acc-fold)
    }

    // ---- LIF1 (own tau): write expanded bf16 frags straight to LDS
#pragma unroll 1
    for (int task = tid; task < 48 * 16; task += 512) {
        int cb = task >> 4;          // c-group of 8: 0..47
        int tpl = task & 15;
        int tp = ptile * 16 + tpl;
        unsigned char* dst = sfrag + (cb >> 2) * 4096 + (((cb & 3) * 16 + tpl) * 16);
        float v[8];
#pragma unroll
        for (int j = 0; j < 8; ++j) v[j] = 0.0f;
#pragma unroll
        for (int t = 0; t < T_; ++t) {
            int gbase = ((t * B_ + b) * C_ + cb * 8) * HW_ + tp;
            unsigned d0 = 0, d1 = 0, d2 = 0, d3 = 0;
#pragma unroll
            for (int j = 0; j < 8; ++j) {
                float xv = x[gbase + j * HW_];
                v[j] = __fadd_rn(v[j], __fdiv_rn(__fsub_rn(xv, v[j]), taur));
                bool s = (__fsub_rn(v[j], 1.0f) >= 0.0f);
                if (s) v[j] = 0.0f;
                unsigned bitv = s ? ((j & 1) ? 0x3F800000u : 0x3F80u) : 0u;
                if (j < 2) d0 |= bitv;
                else if (j < 4) d1 |= bitv;
                else if (j < 6) d2 |= bitv;
                else d3 |= bitv;
            }
            *reinterpret_cast<uint4*>(dst + t * 1024) = make_uint4(d0, d1, d2, d3);
        }
    }
    __syncthreads();

    // ---- conv1
    f32x4 acc[3][T_];
#pragma unroll
    for (int os = 0; os < 3; ++os)
#pragma unroll
        for (int t = 0; t < T_; ++t) acc[os][t] = (f32x4)0.0f;
    unsigned base1 = (unsigned)(er * 2) * 12u * 24u * 512u;
    conv_mfma2(Whif, Wlof, base1, sfrag, acc, wv, lane);

    // ---- epi1: h = x + bn1(y); LIF2 bits; acc := h * rA2 (fold into conv2 C-in)
    unsigned pk[3];
#pragma unroll
    for (int os = 0; os < 3; ++os) {
        float v2s[4] = {0.f, 0.f, 0.f, 0.f};
        unsigned pkos = 0;
#pragma unroll
        for (int t = 0; t < T_; ++t) {
            unsigned nb = 0;
#pragma unroll
            for (int r = 0; r < 4; ++r) {
                int o = wv * 48 + os * 16 + q * 4 + r;
                int gi = ((t * B_ + b) * C_ + o) * HW_ + p;
                float y = acc[os][t][r];
                float h = __fadd_rn(x[gi],
                    __fadd_rn(__fmul_rn(__fadd_rn(y, bns[1 * C_ + o]), bns[0 * C_ + o]),
                              bns[2 * C_ + o]));
                v2s[r] = __fadd_rn(v2s[r], __fdiv_rn(__fsub_rn(h, v2s[r]), taur));
                if (__fsub_rn(v2s[r], 1.0f) >= 0.0f) { nb |= (1u << r); v2s[r] = 0.f; }
                acc[os][t][r] = __fmul_rn(h, bns[6 * C_ + o]);
            }
            unsigned nb_hi = (unsigned)__shfl_down((int)nb, 16);
            pkos |= ((nb | (nb_hi << 4)) & 0xFFu) << (8 * t);
        }
        pk[os] = pkos;
    }
    __syncthreads();   // all conv1 reads of sfrag complete before overwrite

    // ---- write s2 frags (even-q threads own full bytes)
    if ((q & 1) == 0) {
#pragma unroll
        for (int os = 0; os < 3; ++os) {
            int g = wv * 6 + os * 2 + (q >> 1);      // c-group of 8 for conv2 B
            unsigned char* dst = sfrag + (g >> 2) * 4096 + (((g & 3) * 16 + pl) * 16);
#pragma unroll
            for (int t = 0; t < T_; ++t) {
                FragU f = expand_mask((pk[os] >> (8 * t)) & 0xFFu);
                *reinterpret_cast<uint4*>(dst + t * 1024) = f.u;
            }
        }
    }
    __syncthreads();

    // ---- conv2 (acc carries folded residual)
    unsigned base2 = (unsigned)(er * 2 + 1) * 12u * 24u * 512u;
    conv_mfma2(Whif, Wlof, base2, sfrag, acc, wv, lane);

    // ---- epi2: val = (acc + B2)*A2 + BB2 (= bn2(y2) + h); combine via atomics
#pragma unroll
    for (int os = 0; os < 3; ++os)
#pragma unroll
        for (int t = 0; t < T_; ++t)
#pragma unroll
            for (int r = 0; r < 4; ++r) {
                int o = wv * 48 + os * 16 + q * 4 + r;
                int gi = ((t * B_ + b) * C_ + o) * HW_ + p;
                float y = acc[os][t][r];
                float val = __fadd_rn(__fmul_rn(__fadd_rn(y, bns[4 * C_ + o]),
                                                bns[3 * C_ + o]),
                                      bns[5 * C_ + o]);
                atomicAdd(out + gi, __fmul_rn(wr, val));
            }
}

extern "C" void kernel_launch(void* const* d_in, const int* in_sizes, int n_in,
                              void* d_out, int out_size, void* d_ws, size_t ws_size,
                              hipStream_t stream) {
    const float* x    = (const float*)d_in[0];
    const float* rW   = (const float*)d_in[1];
    const float* rb   = (const float*)d_in[2];
    const float* rbs  = (const float*)d_in[3];
    const float* rbb  = (const float*)d_in[4];
    const float* W1   = (const float*)d_in[5];
    const float* b1   = (const float*)d_in[6];
    const float* s1sc = (const float*)d_in[7];
    const float* s1bi = (const float*)d_in[8];
    const float* W2   = (const float*)d_in[9];
    const float* b2   = (const float*)d_in[10];
    const float* s2sc = (const float*)d_in[11];
    const float* s2bi = (const float*)d_in[12];
    float* out = (float*)d_out;

    // ws layout: Whif (4718592 B) | Wlof (4718592 B) | m (24576 floats)
    unsigned short* Whif = (unsigned short*)d_ws;
    unsigned short* Wlof = Whif + 2359296;
    float* m = (float*)((char*)d_ws + 9437184);

    hipLaunchKernelGGL(k_prep, dim3(1152 + B_ * C_), dim3(256), 0, stream,
                       x, W1, W2, Whif, Wlof, m);
    hipMemsetAsync(d_out, 0, out_size, stream);   // atomic-combine needs zeroed out
    hipLaunchKernelGGL(k_expert, dim3(512), dim3(512), 0, stream,
                       x, m, rW, rb, rbs, rbb, Whif, Wlof,
                       b1, s1sc, s1bi, b2, s2sc, s2bi, out);
}

// Round 6
// 189.101 us; speedup vs baseline: 1.1378x; 1.0485x over previous
//
#include <hip/hip_runtime.h>
#include <math.h>

#define T_  4
#define B_  16
#define C_  384
#define HW_ 256
#define E_  8

typedef __attribute__((ext_vector_type(8))) __bf16 bf16x8;
typedef __attribute__((ext_vector_type(4))) float f32x4;

union FragU { uint4 u; bf16x8 v; };

// taus = jnp.linspace(1.5, 4.0, 8) in fp32, endpoint exact
__device__ __forceinline__ float tau_of(int e) {
    if (e == 7) return 4.0f;
    const float delta = 2.5f / 7.0f;
    return __fadd_rn(1.5f, __fmul_rn((float)e, delta));
}

// bits of m (8 spikes) -> bf16x8 {0,1} fragment
__device__ __forceinline__ FragU expand_mask(unsigned m) {
    FragU f;
    f.u.x = ((m & 1u)   ? 0x3F80u : 0u) | ((m & 2u)   ? 0x3F800000u : 0u);
    f.u.y = ((m & 4u)   ? 0x3F80u : 0u) | ((m & 8u)   ? 0x3F800000u : 0u);
    f.u.z = ((m & 16u)  ? 0x3F80u : 0u) | ((m & 32u)  ? 0x3F800000u : 0u);
    f.u.w = ((m & 64u)  ? 0x3F80u : 0u) | ((m & 128u) ? 0x3F800000u : 0u);
    return f;
}

// ---------------- k_prep: coalesced weight-split + router LIF ---------------
// blocks [0,384): weight split, block = (e, cv, og). W tile (16 rows x 384 c)
//   staged through LDS (contiguous coalesced read), fragments written coalesced.
// blocks [384, 384+6144): router LIF (tau=2), unchanged.
__global__ __launch_bounds__(256) void k_prep(const float* __restrict__ x,
        const float* __restrict__ W1, const float* __restrict__ W2,
        unsigned short* __restrict__ Whif, unsigned short* __restrict__ Wlof,
        float* __restrict__ m) {
    if (blockIdx.x < 384) {
        int idx = blockIdx.x;
        int og = idx % 24;
        int cv = (idx / 24) & 1;
        int e = idx / 48;
        const float* Wsrc = (cv == 0 ? W1 : W2) + (size_t)e * C_ * C_
                            + (size_t)og * 16 * C_;
        __shared__ float ld[16 * 388];   // +4 pad: 2-way max on scattered reads
        int tid = threadIdx.x;
        for (int i = tid; i < 16 * 384; i += 256) {
            int r = i >> 8; r = i / 384;             // row
            int c = i - r * 384;
            ld[r * 388 + c] = Wsrc[i];               // flat contiguous global read
        }
        __syncthreads();
        unsigned fbase = ((unsigned)(e * 2 + cv) * 12u * 24u + (unsigned)og) * 512u;
        for (int s = tid; s < 768; s += 256) {       // 12 ksub x 64 lanes
            int l = s & 63;
            int ksub = s >> 6;
            const float* src = ld + (l & 15) * 388 + ksub * 32 + (l >> 4) * 8;
            unsigned hw[8], lw[8];
#pragma unroll
            for (int j = 0; j < 8; ++j) {
                float w = src[j];
                unsigned u = __float_as_uint(w);
                unsigned hi = (u + 0x7FFFu + ((u >> 16) & 1u)) >> 16;
                float hf = __uint_as_float(hi << 16);
                float res = __fsub_rn(w, hf);
                unsigned ru = __float_as_uint(res);
                unsigned lo = (ru + 0x7FFFu + ((ru >> 16) & 1u)) >> 16;
                hw[j] = hi & 0xFFFFu;
                lw[j] = lo & 0xFFFFu;
            }
            size_t dst = (size_t)fbase + (size_t)ksub * 24u * 512u + (size_t)l * 8;
            uint4 hv = make_uint4(hw[0] | (hw[1] << 16), hw[2] | (hw[3] << 16),
                                  hw[4] | (hw[5] << 16), hw[6] | (hw[7] << 16));
            uint4 lv = make_uint4(lw[0] | (lw[1] << 16), lw[2] | (lw[3] << 16),
                                  lw[4] | (lw[5] << 16), lw[6] | (lw[7] << 16));
            *reinterpret_cast<uint4*>(Whif + dst) = hv;
            *reinterpret_cast<uint4*>(Wlof + dst) = lv;
        }
    } else {
        int bc = blockIdx.x - 384;
        int b = bc / C_, c = bc % C_;
        int p = threadIdx.x;
        int wv = threadIdx.x >> 6;
        __shared__ int cnt[T_][4];
        float v = 0.0f;
#pragma unroll
        for (int t = 0; t < T_; ++t) {
            float xv = x[((t * B_ + b) * C_ + c) * HW_ + p];
            v = __fadd_rn(v, __fdiv_rn(__fsub_rn(xv, v), 2.0f));
            bool s = (__fsub_rn(v, 1.0f) >= 0.0f);
            if (s) v = 0.0f;
            unsigned long long mask = __ballot(s);
            if ((threadIdx.x & 63) == 0) cnt[t][wv] = (int)__popcll(mask);
        }
        __syncthreads();
        if (threadIdx.x < T_) {
            int t = threadIdx.x;
            int tot = cnt[t][0] + cnt[t][1] + cnt[t][2] + cnt[t][3];
            m[(t * B_ + b) * C_ + c] = (float)tot * 0.00390625f;
        }
    }
}

// ---------------- conv core: B-frags via ds_read_b128 from LDS (proven) -----
__device__ __forceinline__ void conv_mfma2(const unsigned short* __restrict__ Whif,
                                           const unsigned short* __restrict__ Wlof,
                                           unsigned base,
                                           const unsigned char* __restrict__ sf,
                                           f32x4 (&acc)[3][4],
                                           int wv, int lane) {
    const unsigned lane8 = (unsigned)lane * 8u;
    const unsigned wbase = base + (unsigned)(wv * 3) * 512u + lane8;
    const unsigned char* fp = sf + lane * 16;
    FragU c0f, c1f, c2f, n0f, n1f, n2f, bf[T_];
    c0f.u = *reinterpret_cast<const uint4*>(Wlof + wbase);
    c1f.u = *reinterpret_cast<const uint4*>(Wlof + wbase + 512u);
    c2f.u = *reinterpret_cast<const uint4*>(Wlof + wbase + 1024u);
#pragma unroll 1
    for (int ksub = 0; ksub < 12; ++ksub) {
        unsigned fo = wbase + (unsigned)ksub * 24u * 512u;
        const unsigned char* fk = fp + ksub * 4096;
#pragma unroll
        for (int t = 0; t < T_; ++t)
            bf[t].u = *reinterpret_cast<const uint4*>(fk + t * 1024);
        n0f.u = *reinterpret_cast<const uint4*>(Whif + fo);
        n1f.u = *reinterpret_cast<const uint4*>(Whif + fo + 512u);
        n2f.u = *reinterpret_cast<const uint4*>(Whif + fo + 1024u);
#pragma unroll
        for (int t = 0; t < T_; ++t) {
            acc[0][t] = __builtin_amdgcn_mfma_f32_16x16x32_bf16(c0f.v, bf[t].v, acc[0][t], 0, 0, 0);
            acc[1][t] = __builtin_amdgcn_mfma_f32_16x16x32_bf16(c1f.v, bf[t].v, acc[1][t], 0, 0, 0);
            acc[2][t] = __builtin_amdgcn_mfma_f32_16x16x32_bf16(c2f.v, bf[t].v, acc[2][t], 0, 0, 0);
        }
        if (ksub < 11) {
            unsigned fn = fo + 24u * 512u;
            c0f.u = *reinterpret_cast<const uint4*>(Wlof + fn);
            c1f.u = *reinterpret_cast<const uint4*>(Wlof + fn + 512u);
            c2f.u = *reinterpret_cast<const uint4*>(Wlof + fn + 1024u);
        }
#pragma unroll
        for (int t = 0; t < T_; ++t) {
            acc[0][t] = __builtin_amdgcn_mfma_f32_16x16x32_bf16(n0f.v, bf[t].v, acc[0][t], 0, 0, 0);
            acc[1][t] = __builtin_amdgcn_mfma_f32_16x16x32_bf16(n1f.v, bf[t].v, acc[1][t], 0, 0, 0);
            acc[2][t] = __builtin_amdgcn_mfma_f32_16x16x32_bf16(n2f.v, bf[t].v, acc[2][t], 0, 0, 0);
        }
    }
}

// ---------------- k_expert v4: round-0 shell + LDS-frag conv ----------------
// grid 256 (b x ptile), 512 threads, launch_bounds (512,2) -- the only proven
// sane-regalloc config. One block owns a tile: both top-2 experts run serially
// (rank0 then rank1); unique writer, rank1 does same-thread out += (L2-hot).
// Spike B-operands are pre-expanded bf16 fragments in LDS (ds_read_b128,
// 0 bank conflicts, VGPR 104 -- both measured in rounds 4-5), expanded once
// per conv pass by all 512 threads instead of redundantly per-wave.
__global__ __launch_bounds__(512, 2) void k_expert(
        const float* __restrict__ x, const float* __restrict__ m,
        const float* __restrict__ rW, const float* __restrict__ rb,
        const float* __restrict__ rbs, const float* __restrict__ rbb,
        const unsigned short* __restrict__ Whif, const unsigned short* __restrict__ Wlof,
        const float* __restrict__ b1, const float* __restrict__ s1sc, const float* __restrict__ s1bi,
        const float* __restrict__ b2, const float* __restrict__ s2sc, const float* __restrict__ s2bi,
        float* __restrict__ out) {
    int blk = blockIdx.x;
    int b = (blk & 7) | (((blk >> 3) & 1) << 3);   // XCD = b&7: x/L2 affinity
    int ptile = blk >> 4;

    __shared__ __align__(16) unsigned char sfrag[49152];   // 48 KB B-fragments
    __shared__ unsigned char s1m1[3072];   // rank1 LIF1 byte masks
    __shared__ unsigned char s2mb[3072];   // LIF2 byte masks (reused r0/r1)
    __shared__ float bns[2 * 7 * C_];      // [rank][A1,B1,BB1,A2,B2,BB2,rA2][o]
    __shared__ float lg[E_];
    __shared__ float wsl[2];
    __shared__ int esl[2];

    int tid = threadIdx.x;
    int wv = tid >> 6;            // wave 0..7
    int lane = tid & 63;
    int q = lane >> 4;
    int pl = lane & 15;
    int p = ptile * 16 + pl;
    float denom = sqrtf(__fadd_rn(1.0f, 1e-5f));

    // ---- inline route (wave 0), identical arithmetic to previous versions
    if (tid < 64) {
        int combo = tid & 31, half = tid >> 5;
        int e = combo >> 2, t = combo & 3;
        float dot = 0.0f;
        int c0 = half * 192;
        for (int c = 0; c < 192; ++c)
            dot = fmaf(rW[e * C_ + c0 + c], m[(t * B_ + b) * C_ + c0 + c], dot);
        dot += __shfl_down(dot, 32);
        float Ar = __fdiv_rn(rbs[e], denom);
        float lt = __fadd_rn(__fmul_rn(__fadd_rn(dot, rb[e]), Ar), rbb[e]);
        lt = __fadd_rn(lt, __shfl_xor(lt, 1));
        lt = __fadd_rn(lt, __shfl_xor(lt, 2));
        if (half == 0 && t == 0) lg[e] = __fmul_rn(lt, 0.25f);
    }
    __syncthreads();
    if (tid == 0) {
        float pr[E_];
        float mx = lg[0];
        for (int i = 1; i < E_; ++i) mx = fmaxf(mx, lg[i]);
        float s = 0.0f;
        for (int i = 0; i < E_; ++i) { pr[i] = expf(__fsub_rn(lg[i], mx)); s = __fadd_rn(s, pr[i]); }
        for (int i = 0; i < E_; ++i) pr[i] = __fdiv_rn(pr[i], s);
        int i0 = 0;
        for (int i = 1; i < E_; ++i) if (pr[i] > pr[i0]) i0 = i;
        int i1 = (i0 == 0) ? 1 : 0;
        for (int i = 0; i < E_; ++i) if (i != i0 && pr[i] > pr[i1]) i1 = i;
        float s2 = __fadd_rn(pr[i0], pr[i1]);
        wsl[0] = __fdiv_rn(pr[i0], s2);
        wsl[1] = __fdiv_rn(pr[i1], s2);
        esl[0] = i0;
        esl[1] = i1;
    }
    __syncthreads();

    int e0 = esl[0], e1 = esl[1];
    float wr0 = wsl[0], wr1 = wsl[1];
    float tau0 = tau_of(e0), tau1 = tau_of(e1);

    // ---- BN staging, both ranks
    if (tid < C_) {
#pragma unroll
        for (int r_ = 0; r_ < 2; ++r_) {
            int er = (r_ == 0) ? e0 : e1;
            float* bp = bns + r_ * 7 * C_;
            float a1 = __fdiv_rn(s1sc[er * C_ + tid], denom);
            float a2 = __fdiv_rn(s2sc[er * C_ + tid], denom);
            bp[0 * C_ + tid] = a1;
            bp[1 * C_ + tid] = b1[er * C_ + tid];
            bp[2 * C_ + tid] = s1bi[er * C_ + tid];
            bp[3 * C_ + tid] = a2;
            bp[4 * C_ + tid] = b2[er * C_ + tid];
            bp[5 * C_ + tid] = s2bi[er * C_ + tid];
            bp[6 * C_ + tid] = __fdiv_rn(1.0f, a2);   // rA2 (acc-fold)
        }
    }

    // ---- LIF1 dual-tau (x read once): rank0 expanded frags + rank1 byte masks
#pragma unroll 1
    for (int task = tid; task < 48 * 16; task += 512) {
        int cb = task >> 4;          // c-group of 8: 0..47
        int tpl = task & 15;
        int tp = ptile * 16 + tpl;
        unsigned char* dst0 = sfrag + (cb >> 2) * 4096 + (((cb & 3) * 16 + tpl) * 16);
        float va[8], vb[8];
#pragma unroll
        for (int j = 0; j < 8; ++j) { va[j] = 0.0f; vb[j] = 0.0f; }
#pragma unroll
        for (int t = 0; t < T_; ++t) {
            int gbase = ((t * B_ + b) * C_ + cb * 8) * HW_ + tp;
            unsigned d0 = 0, d1 = 0, d2 = 0, d3 = 0, mb1 = 0;
#pragma unroll
            for (int j = 0; j < 8; ++j) {
                float xv = x[gbase + j * HW_];
                va[j] = __fadd_rn(va[j], __fdiv_rn(__fsub_rn(xv, va[j]), tau0));
                bool s0 = (__fsub_rn(va[j], 1.0f) >= 0.0f);
                if (s0) va[j] = 0.0f;
                unsigned bitv = s0 ? ((j & 1) ? 0x3F800000u : 0x3F80u) : 0u;
                if (j < 2) d0 |= bitv;
                else if (j < 4) d1 |= bitv;
                else if (j < 6) d2 |= bitv;
                else d3 |= bitv;
                vb[j] = __fadd_rn(vb[j], __fdiv_rn(__fsub_rn(xv, vb[j]), tau1));
                bool s1 = (__fsub_rn(vb[j], 1.0f) >= 0.0f);
                if (s1) { mb1 |= (1u << j); vb[j] = 0.0f; }
            }
            *reinterpret_cast<uint4*>(dst0 + t * 1024) = make_uint4(d0, d1, d2, d3);
            s1m1[(t * 16 + tpl) * 48 + cb] = (unsigned char)mb1;
        }
    }
    __syncthreads();

    f32x4 acc[3][T_];

    // ================= RANK 0 =================
#pragma unroll
    for (int os = 0; os < 3; ++os)
#pragma unroll
        for (int t = 0; t < T_; ++t) acc[os][t] = (f32x4)0.0f;
    conv_mfma2(Whif, Wlof, (unsigned)(e0 * 2) * 12u * 24u * 512u, sfrag, acc, wv, lane);

    {   // epi1 r0: h = x + bn1(y); LIF2 masks -> s2mb; acc := h * rA2
        const float* bp = bns;
#pragma unroll
        for (int os = 0; os < 3; ++os) {
            float v2s[4] = {0.f, 0.f, 0.f, 0.f};
#pragma unroll
            for (int t = 0; t < T_; ++t) {
                unsigned nb = 0;
#pragma unroll
                for (int r = 0; r < 4; ++r) {
                    int o = wv * 48 + os * 16 + q * 4 + r;
                    int gi = ((t * B_ + b) * C_ + o) * HW_ + p;
                    float y = acc[os][t][r];
                    float h = __fadd_rn(x[gi],
                        __fadd_rn(__fmul_rn(__fadd_rn(y, bp[1 * C_ + o]), bp[0 * C_ + o]),
                                  bp[2 * C_ + o]));
                    v2s[r] = __fadd_rn(v2s[r], __fdiv_rn(__fsub_rn(h, v2s[r]), tau0));
                    if (__fsub_rn(v2s[r], 1.0f) >= 0.0f) { nb |= (1u << r); v2s[r] = 0.f; }
                    acc[os][t][r] = __fmul_rn(h, bp[6 * C_ + o]);
                }
                unsigned nb_hi = (unsigned)__shfl_down((int)nb, 16);
                if ((q & 1) == 0)
                    s2mb[(t * 16 + pl) * 48 + (wv * 6 + os * 2 + (q >> 1))] =
                        (unsigned char)(nb | (nb_hi << 4));
            }
        }
    }
    __syncthreads();   // conv1-r0 sfrag reads done; s2mb complete

    // expand s2mb -> sfrag (6 slots/thread)
#pragma unroll
    for (int it = 0; it < 6; ++it) {
        int s = tid + it * 512;
        int l = s & 63, t = (s >> 6) & 3, ks = s >> 8;
        FragU f = expand_mask(s2mb[(t * 16 + (l & 15)) * 48 + ks * 4 + (l >> 4)]);
        *reinterpret_cast<uint4*>(sfrag + ks * 4096 + t * 1024 + l * 16) = f.u;
    }
    __syncthreads();

    conv_mfma2(Whif, Wlof, (unsigned)(e0 * 2 + 1) * 12u * 24u * 512u, sfrag, acc, wv, lane);

    {   // epi2 r0: out = wr0 * ((acc + B2)*A2 + BB2)   (= wr0*(bn2(y2)+h))
        const float* bp = bns;
#pragma unroll
        for (int os = 0; os < 3; ++os)
#pragma unroll
            for (int t = 0; t < T_; ++t)
#pragma unroll
                for (int r = 0; r < 4; ++r) {
                    int o = wv * 48 + os * 16 + q * 4 + r;
                    int gi = ((t * B_ + b) * C_ + o) * HW_ + p;
                    float y = acc[os][t][r];
                    float val = __fadd_rn(__fmul_rn(__fadd_rn(y, bp[4 * C_ + o]),
                                                    bp[3 * C_ + o]),
                                          bp[5 * C_ + o]);
                    out[gi] = __fmul_rn(wr0, val);
                }
    }
    __syncthreads();   // conv2-r0 sfrag reads done

    // ================= RANK 1 =================
    // expand s1m1 -> sfrag
#pragma unroll
    for (int it = 0; it < 6; ++it) {
        int s = tid + it * 512;
        int l = s & 63, t = (s >> 6) & 3, ks = s >> 8;
        FragU f = expand_mask(s1m1[(t * 16 + (l & 15)) * 48 + ks * 4 + (l >> 4)]);
        *reinterpret_cast<uint4*>(sfrag + ks * 4096 + t * 1024 + l * 16) = f.u;
    }
    __syncthreads();

#pragma unroll
    for (int os = 0; os < 3; ++os)
#pragma unroll
        for (int t = 0; t < T_; ++t) acc[os][t] = (f32x4)0.0f;
    conv_mfma2(Whif, Wlof, (unsigned)(e1 * 2) * 12u * 24u * 512u, sfrag, acc, wv, lane);

    {   // epi1 r1
        const float* bp = bns + 7 * C_;
#pragma unroll
        for (int os = 0; os < 3; ++os) {
            float v2s[4] = {0.f, 0.f, 0.f, 0.f};
#pragma unroll
            for (int t = 0; t < T_; ++t) {
                unsigned nb = 0;
#pragma unroll
                for (int r = 0; r < 4; ++r) {
                    int o = wv * 48 + os * 16 + q * 4 + r;
                    int gi = ((t * B_ + b) * C_ + o) * HW_ + p;
                    float y = acc[os][t][r];
                    float h = __fadd_rn(x[gi],
                        __fadd_rn(__fmul_rn(__fadd_rn(y, bp[1 * C_ + o]), bp[0 * C_ + o]),
                                  bp[2 * C_ + o]));
                    v2s[r] = __fadd_rn(v2s[r], __fdiv_rn(__fsub_rn(h, v2s[r]), tau1));
                    if (__fsub_rn(v2s[r], 1.0f) >= 0.0f) { nb |= (1u << r); v2s[r] = 0.f; }
                    acc[os][t][r] = __fmul_rn(h, bp[6 * C_ + o]);
                }
                unsigned nb_hi = (unsigned)__shfl_down((int)nb, 16);
                if ((q & 1) == 0)
                    s2mb[(t * 16 + pl) * 48 + (wv * 6 + os * 2 + (q >> 1))] =
                        (unsigned char)(nb | (nb_hi << 4));
            }
        }
    }
    __syncthreads();

    // expand s2mb -> sfrag
#pragma unroll
    for (int it = 0; it < 6; ++it) {
        int s = tid + it * 512;
        int l = s & 63, t = (s >> 6) & 3, ks = s >> 8;
        FragU f = expand_mask(s2mb[(t * 16 + (l & 15)) * 48 + ks * 4 + (l >> 4)]);
        *reinterpret_cast<uint4*>(sfrag + ks * 4096 + t * 1024 + l * 16) = f.u;
    }
    __syncthreads();

    conv_mfma2(Whif, Wlof, (unsigned)(e1 * 2 + 1) * 12u * 24u * 512u, sfrag, acc, wv, lane);

    {   // epi2 r1: out += wr1 * val (same thread wrote r0's value -> ordered)
        const float* bp = bns + 7 * C_;
#pragma unroll
        for (int os = 0; os < 3; ++os)
#pragma unroll
            for (int t = 0; t < T_; ++t)
#pragma unroll
                for (int r = 0; r < 4; ++r) {
                    int o = wv * 48 + os * 16 + q * 4 + r;
                    int gi = ((t * B_ + b) * C_ + o) * HW_ + p;
                    float y = acc[os][t][r];
                    float val = __fadd_rn(__fmul_rn(__fadd_rn(y, bp[4 * C_ + o]),
                                                    bp[3 * C_ + o]),
                                          bp[5 * C_ + o]);
                    out[gi] = __fadd_rn(out[gi], __fmul_rn(wr1, val));
                }
    }
}

extern "C" void kernel_launch(void* const* d_in, const int* in_sizes, int n_in,
                              void* d_out, int out_size, void* d_ws, size_t ws_size,
                              hipStream_t stream) {
    const float* x    = (const float*)d_in[0];
    const float* rW   = (const float*)d_in[1];
    const float* rb   = (const float*)d_in[2];
    const float* rbs  = (const float*)d_in[3];
    const float* rbb  = (const float*)d_in[4];
    const float* W1   = (const float*)d_in[5];
    const float* b1   = (const float*)d_in[6];
    const float* s1sc = (const float*)d_in[7];
    const float* s1bi = (const float*)d_in[8];
    const float* W2   = (const float*)d_in[9];
    const float* b2   = (const float*)d_in[10];
    const float* s2sc = (const float*)d_in[11];
    const float* s2bi = (const float*)d_in[12];
    float* out = (float*)d_out;

    // ws layout: Whif (4718592 B) | Wlof (4718592 B) | m (24576 floats)
    unsigned short* Whif = (unsigned short*)d_ws;
    unsigned short* Wlof = Whif + 2359296;
    float* m = (float*)((char*)d_ws + 9437184);

    hipLaunchKernelGGL(k_prep, dim3(384 + B_ * C_), dim3(256), 0, stream,
                       x, W1, W2, Whif, Wlof, m);
    hipLaunchKernelGGL(k_expert, dim3(256), dim3(512), 0, stream,
                       x, m, rW, rb, rbs, rbb, Whif, Wlof,
                       b1, s1sc, s1bi, b2, s2sc, s2bi, out);
}

// Round 7
// 182.802 us; speedup vs baseline: 1.1770x; 1.0345x over previous
//
#include <hip/hip_runtime.h>
#include <math.h>

#define T_  4
#define B_  16
#define C_  384
#define HW_ 256
#define E_  8

typedef __attribute__((ext_vector_type(8))) __bf16 bf16x8;
typedef __attribute__((ext_vector_type(4))) float f32x4;

union FragU { uint4 u; bf16x8 v; };

// taus = jnp.linspace(1.5, 4.0, 8) in fp32, endpoint exact
__device__ __forceinline__ float tau_of(int e) {
    if (e == 7) return 4.0f;
    const float delta = 2.5f / 7.0f;
    return __fadd_rn(1.5f, __fmul_rn((float)e, delta));
}

// bits of m (8 spikes) -> bf16x8 {0,1} fragment
__device__ __forceinline__ FragU expand_mask(unsigned m) {
    FragU f;
    f.u.x = ((m & 1u)   ? 0x3F80u : 0u) | ((m & 2u)   ? 0x3F800000u : 0u);
    f.u.y = ((m & 4u)   ? 0x3F80u : 0u) | ((m & 8u)   ? 0x3F800000u : 0u);
    f.u.z = ((m & 16u)  ? 0x3F80u : 0u) | ((m & 32u)  ? 0x3F800000u : 0u);
    f.u.w = ((m & 64u)  ? 0x3F80u : 0u) | ((m & 128u) ? 0x3F800000u : 0u);
    return f;
}

// ---------------- k_prep: coalesced weight-split + router LIF (round-6) -----
__global__ __launch_bounds__(256) void k_prep(const float* __restrict__ x,
        const float* __restrict__ W1, const float* __restrict__ W2,
        unsigned short* __restrict__ Whif, unsigned short* __restrict__ Wlof,
        float* __restrict__ m) {
    if (blockIdx.x < 384) {
        int idx = blockIdx.x;
        int og = idx % 24;
        int cv = (idx / 24) & 1;
        int e = idx / 48;
        const float* Wsrc = (cv == 0 ? W1 : W2) + (size_t)e * C_ * C_
                            + (size_t)og * 16 * C_;
        __shared__ float ld[16 * 388];
        int tid = threadIdx.x;
        for (int i = tid; i < 16 * 384; i += 256) {
            int r = i / 384;
            int c = i - r * 384;
            ld[r * 388 + c] = Wsrc[i];
        }
        __syncthreads();
        unsigned fbase = ((unsigned)(e * 2 + cv) * 12u * 24u + (unsigned)og) * 512u;
        for (int s = tid; s < 768; s += 256) {       // 12 ksub x 64 lanes
            int l = s & 63;
            int ksub = s >> 6;
            const float* src = ld + (l & 15) * 388 + ksub * 32 + (l >> 4) * 8;
            unsigned hw[8], lw[8];
#pragma unroll
            for (int j = 0; j < 8; ++j) {
                float w = src[j];
                unsigned u = __float_as_uint(w);
                unsigned hi = (u + 0x7FFFu + ((u >> 16) & 1u)) >> 16;
                float hf = __uint_as_float(hi << 16);
                float res = __fsub_rn(w, hf);
                unsigned ru = __float_as_uint(res);
                unsigned lo = (ru + 0x7FFFu + ((ru >> 16) & 1u)) >> 16;
                hw[j] = hi & 0xFFFFu;
                lw[j] = lo & 0xFFFFu;
            }
            size_t dst = (size_t)fbase + (size_t)ksub * 24u * 512u + (size_t)l * 8;
            uint4 hv = make_uint4(hw[0] | (hw[1] << 16), hw[2] | (hw[3] << 16),
                                  hw[4] | (hw[5] << 16), hw[6] | (hw[7] << 16));
            uint4 lv = make_uint4(lw[0] | (lw[1] << 16), lw[2] | (lw[3] << 16),
                                  lw[4] | (lw[5] << 16), lw[6] | (lw[7] << 16));
            *reinterpret_cast<uint4*>(Whif + dst) = hv;
            *reinterpret_cast<uint4*>(Wlof + dst) = lv;
        }
    } else {
        int bc = blockIdx.x - 384;
        int b = bc / C_, c = bc % C_;
        int p = threadIdx.x;
        int wv = threadIdx.x >> 6;
        __shared__ int cnt[T_][4];
        float v = 0.0f;
#pragma unroll
        for (int t = 0; t < T_; ++t) {
            float xv = x[((t * B_ + b) * C_ + c) * HW_ + p];
            v = __fadd_rn(v, __fdiv_rn(__fsub_rn(xv, v), 2.0f));
            bool s = (__fsub_rn(v, 1.0f) >= 0.0f);
            if (s) v = 0.0f;
            unsigned long long mask = __ballot(s);
            if ((threadIdx.x & 63) == 0) cnt[t][wv] = (int)__popcll(mask);
        }
        __syncthreads();
        if (threadIdx.x < T_) {
            int t = threadIdx.x;
            int tot = cnt[t][0] + cnt[t][1] + cnt[t][2] + cnt[t][3];
            m[(t * B_ + b) * C_ + c] = (float)tot * 0.00390625f;
        }
    }
}

// ---------------- conv core v3: bf-rotated, low-pressure --------------------
// B-frag loaded per-t (2-reg rotate) instead of bf[4] held across lo+hi loops.
// lo and hi MFMAs interleaved per t. Live set ~ acc48 + W24 + bf8.
__device__ __forceinline__ void conv_mfma3(const unsigned short* __restrict__ Whif,
                                           const unsigned short* __restrict__ Wlof,
                                           unsigned base,
                                           const unsigned char* __restrict__ sf,
                                           f32x4 (&acc)[3][4],
                                           int wv, int lane) {
    const unsigned wbase = base + (unsigned)(wv * 3) * 512u + (unsigned)lane * 8u;
    const unsigned char* fp = sf + lane * 16;
    FragU c0, c1, c2, n0, n1, n2, f0, f1;
    c0.u = *reinterpret_cast<const uint4*>(Wlof + wbase);
    c1.u = *reinterpret_cast<const uint4*>(Wlof + wbase + 512u);
    c2.u = *reinterpret_cast<const uint4*>(Wlof + wbase + 1024u);
#pragma unroll 1
    for (int ksub = 0; ksub < 12; ++ksub) {
        unsigned fo = wbase + (unsigned)ksub * 24u * 512u;
        const unsigned char* fk = fp + ksub * 4096;
        n0.u = *reinterpret_cast<const uint4*>(Whif + fo);
        n1.u = *reinterpret_cast<const uint4*>(Whif + fo + 512u);
        n2.u = *reinterpret_cast<const uint4*>(Whif + fo + 1024u);
        f0.u = *reinterpret_cast<const uint4*>(fk);
#pragma unroll
        for (int t = 0; t < T_; ++t) {
            if (t < 3) f1.u = *reinterpret_cast<const uint4*>(fk + (t + 1) * 1024);
            acc[0][t] = __builtin_amdgcn_mfma_f32_16x16x32_bf16(c0.v, f0.v, acc[0][t], 0, 0, 0);
            acc[1][t] = __builtin_amdgcn_mfma_f32_16x16x32_bf16(c1.v, f0.v, acc[1][t], 0, 0, 0);
            acc[2][t] = __builtin_amdgcn_mfma_f32_16x16x32_bf16(c2.v, f0.v, acc[2][t], 0, 0, 0);
            acc[0][t] = __builtin_amdgcn_mfma_f32_16x16x32_bf16(n0.v, f0.v, acc[0][t], 0, 0, 0);
            acc[1][t] = __builtin_amdgcn_mfma_f32_16x16x32_bf16(n1.v, f0.v, acc[1][t], 0, 0, 0);
            acc[2][t] = __builtin_amdgcn_mfma_f32_16x16x32_bf16(n2.v, f0.v, acc[2][t], 0, 0, 0);
            f0 = f1;
        }
        if (ksub < 11) {
            unsigned fn = fo + 24u * 512u;
            c0.u = *reinterpret_cast<const uint4*>(Wlof + fn);
            c1.u = *reinterpret_cast<const uint4*>(Wlof + fn + 512u);
            c2.u = *reinterpret_cast<const uint4*>(Wlof + fn + 1024u);
        }
    }
}

// ---------------- k_expert v5: round-0 shell + LDS frags + LDS combine ------
// grid 256 (b x ptile), 512 thr, (512,2). Serial ranks; rank0 result parked in
// LDS pcomb (f32), rank1 adds and does the single out store (no readback, no
// atomics). Conv B-operands pre-expanded in LDS; bf-rotated core keeps VGPR
// demand well under the 128 budget (v4 sat AT 128 -> spill -> 83 MB scratch).
__global__ __launch_bounds__(512, 2) void k_expert(
        const float* __restrict__ x, const float* __restrict__ m,
        const float* __restrict__ rW, const float* __restrict__ rb,
        const float* __restrict__ rbs, const float* __restrict__ rbb,
        const unsigned short* __restrict__ Whif, const unsigned short* __restrict__ Wlof,
        const float* __restrict__ b1, const float* __restrict__ s1sc, const float* __restrict__ s1bi,
        const float* __restrict__ b2, const float* __restrict__ s2sc, const float* __restrict__ s2bi,
        float* __restrict__ out) {
    int blk = blockIdx.x;
    int b = (blk & 7) | (((blk >> 3) & 1) << 3);   // XCD = b&7: x/L2 affinity
    int ptile = blk >> 4;

    __shared__ __align__(16) unsigned char sfrag[49152];   // 48 KB B-fragments
    __shared__ float pcomb[T_ * C_ * 16];                  // 96 KB rank0 partial
    __shared__ float bns[7 * C_];          // one rank at a time (re-staged)
    __shared__ unsigned char s1m1[3072];   // rank1 LIF1 byte masks
    __shared__ float lg[E_];
    __shared__ float wsl[2];
    __shared__ int esl[2];

    int tid = threadIdx.x;
    int wv = tid >> 6;            // wave 0..7
    int lane = tid & 63;
    int q = lane >> 4;
    int pl = lane & 15;
    int p = ptile * 16 + pl;
    float denom = sqrtf(__fadd_rn(1.0f, 1e-5f));

    // ---- inline route (wave 0), round-0 verbatim
    if (tid < 64) {
        int combo = tid & 31, half = tid >> 5;
        int e = combo >> 2, t = combo & 3;
        float dot = 0.0f;
        int c0 = half * 192;
        for (int c = 0; c < 192; ++c)
            dot = fmaf(rW[e * C_ + c0 + c], m[(t * B_ + b) * C_ + c0 + c], dot);
        dot += __shfl_down(dot, 32);
        float Ar = __fdiv_rn(rbs[e], denom);
        float lt = __fadd_rn(__fmul_rn(__fadd_rn(dot, rb[e]), Ar), rbb[e]);
        lt = __fadd_rn(lt, __shfl_xor(lt, 1));
        lt = __fadd_rn(lt, __shfl_xor(lt, 2));
        if (half == 0 && t == 0) lg[e] = __fmul_rn(lt, 0.25f);
    }
    __syncthreads();
    if (tid == 0) {
        float pr[E_];
        float mx = lg[0];
        for (int i = 1; i < E_; ++i) mx = fmaxf(mx, lg[i]);
        float s = 0.0f;
        for (int i = 0; i < E_; ++i) { pr[i] = expf(__fsub_rn(lg[i], mx)); s = __fadd_rn(s, pr[i]); }
        for (int i = 0; i < E_; ++i) pr[i] = __fdiv_rn(pr[i], s);
        int i0 = 0;
        for (int i = 1; i < E_; ++i) if (pr[i] > pr[i0]) i0 = i;
        int i1 = (i0 == 0) ? 1 : 0;
        for (int i = 0; i < E_; ++i) if (i != i0 && pr[i] > pr[i1]) i1 = i;
        float s2 = __fadd_rn(pr[i0], pr[i1]);
        wsl[0] = __fdiv_rn(pr[i0], s2);
        wsl[1] = __fdiv_rn(pr[i1], s2);
        esl[0] = i0;
        esl[1] = i1;
    }
    __syncthreads();

    int e0 = esl[0], e1 = esl[1];
    float wr0 = wsl[0], wr1 = wsl[1];
    float tau0 = tau_of(e0), tau1 = tau_of(e1);

    // ---- BN staging rank0
    if (tid < C_) {
        float a1 = __fdiv_rn(s1sc[e0 * C_ + tid], denom);
        float a2 = __fdiv_rn(s2sc[e0 * C_ + tid], denom);
        bns[0 * C_ + tid] = a1;
        bns[1 * C_ + tid] = b1[e0 * C_ + tid];
        bns[2 * C_ + tid] = s1bi[e0 * C_ + tid];
        bns[3 * C_ + tid] = a2;
        bns[4 * C_ + tid] = b2[e0 * C_ + tid];
        bns[5 * C_ + tid] = s2bi[e0 * C_ + tid];
        bns[6 * C_ + tid] = __fdiv_rn(1.0f, a2);   // rA2 (acc-fold)
    }

    // ---- LIF1 dual-tau (x read once): rank0 expanded frags + rank1 byte masks
#pragma unroll 1
    for (int task = tid; task < 48 * 16; task += 512) {
        int cb = task >> 4;          // c-group of 8: 0..47
        int tpl = task & 15;
        int tp = ptile * 16 + tpl;
        unsigned char* dst0 = sfrag + (cb >> 2) * 4096 + (((cb & 3) * 16 + tpl) * 16);
        float va[8], vb[8];
#pragma unroll
        for (int j = 0; j < 8; ++j) { va[j] = 0.0f; vb[j] = 0.0f; }
#pragma unroll
        for (int t = 0; t < T_; ++t) {
            int gbase = ((t * B_ + b) * C_ + cb * 8) * HW_ + tp;
            unsigned d0 = 0, d1 = 0, d2 = 0, d3 = 0, mb1 = 0;
#pragma unroll
            for (int j = 0; j < 8; ++j) {
                float xv = x[gbase + j * HW_];
                va[j] = __fadd_rn(va[j], __fdiv_rn(__fsub_rn(xv, va[j]), tau0));
                bool s0 = (__fsub_rn(va[j], 1.0f) >= 0.0f);
                if (s0) va[j] = 0.0f;
                unsigned bitv = s0 ? ((j & 1) ? 0x3F800000u : 0x3F80u) : 0u;
                if (j < 2) d0 |= bitv;
                else if (j < 4) d1 |= bitv;
                else if (j < 6) d2 |= bitv;
                else d3 |= bitv;
                vb[j] = __fadd_rn(vb[j], __fdiv_rn(__fsub_rn(xv, vb[j]), tau1));
                bool s1 = (__fsub_rn(vb[j], 1.0f) >= 0.0f);
                if (s1) { mb1 |= (1u << j); vb[j] = 0.0f; }
            }
            *reinterpret_cast<uint4*>(dst0 + t * 1024) = make_uint4(d0, d1, d2, d3);
            s1m1[(t * 16 + tpl) * 48 + cb] = (unsigned char)mb1;
        }
    }
    __syncthreads();

    f32x4 acc[3][T_];
    unsigned pk[3];

    // ================= RANK 0 =================
#pragma unroll
    for (int os = 0; os < 3; ++os)
#pragma unroll
        for (int t = 0; t < T_; ++t) acc[os][t] = (f32x4)0.0f;
    conv_mfma3(Whif, Wlof, (unsigned)(e0 * 2) * 12u * 24u * 512u, sfrag, acc, wv, lane);

    {   // epi1 r0: h = x + bn1(y); LIF2 masks -> pk regs; acc := h * rA2
#pragma unroll
        for (int os = 0; os < 3; ++os) {
            float v2s[4] = {0.f, 0.f, 0.f, 0.f};
            unsigned pkos = 0;
#pragma unroll
            for (int t = 0; t < T_; ++t) {
                unsigned nb = 0;
#pragma unroll
                for (int r = 0; r < 4; ++r) {
                    int o = wv * 48 + os * 16 + q * 4 + r;
                    int gi = ((t * B_ + b) * C_ + o) * HW_ + p;
                    float y = acc[os][t][r];
                    float h = __fadd_rn(x[gi],
                        __fadd_rn(__fmul_rn(__fadd_rn(y, bns[1 * C_ + o]), bns[0 * C_ + o]),
                                  bns[2 * C_ + o]));
                    v2s[r] = __fadd_rn(v2s[r], __fdiv_rn(__fsub_rn(h, v2s[r]), tau0));
                    if (__fsub_rn(v2s[r], 1.0f) >= 0.0f) { nb |= (1u << r); v2s[r] = 0.f; }
                    acc[os][t][r] = __fmul_rn(h, bns[6 * C_ + o]);
                }
                unsigned nb_hi = (unsigned)__shfl_down((int)nb, 16);
                pkos |= ((nb | (nb_hi << 4)) & 0xFFu) << (8 * t);
            }
            pk[os] = pkos;
        }
    }
    __syncthreads();   // conv1-r0 sfrag reads done before overwrite

    if ((q & 1) == 0) {   // expand pk -> sfrag (even-q threads own full bytes)
#pragma unroll
        for (int os = 0; os < 3; ++os) {
            int g = wv * 6 + os * 2 + (q >> 1);
            unsigned char* dst = sfrag + (g >> 2) * 4096 + (((g & 3) * 16 + pl) * 16);
#pragma unroll
            for (int t = 0; t < T_; ++t) {
                FragU f = expand_mask((pk[os] >> (8 * t)) & 0xFFu);
                *reinterpret_cast<uint4*>(dst + t * 1024) = f.u;
            }
        }
    }
    __syncthreads();

    conv_mfma3(Whif, Wlof, (unsigned)(e0 * 2 + 1) * 12u * 24u * 512u, sfrag, acc, wv, lane);

    {   // epi2 r0: pcomb = wr0 * ((acc + B2)*A2 + BB2)
#pragma unroll
        for (int os = 0; os < 3; ++os)
#pragma unroll
            for (int t = 0; t < T_; ++t)
#pragma unroll
                for (int r = 0; r < 4; ++r) {
                    int o = wv * 48 + os * 16 + q * 4 + r;
                    float y = acc[os][t][r];
                    float val = __fadd_rn(__fmul_rn(__fadd_rn(y, bns[4 * C_ + o]),
                                                    bns[3 * C_ + o]),
                                          bns[5 * C_ + o]);
                    pcomb[(t * C_ + o) * 16 + pl] = __fmul_rn(wr0, val);
                }
    }
    __syncthreads();   // conv2-r0 sfrag reads + pcomb writes complete

    // ================= RANK 1 =================
    // expand s1m1 -> sfrag (all threads, 6 slots each) + restage BN for e1
#pragma unroll
    for (int it = 0; it < 6; ++it) {
        int s = tid + it * 512;
        int l = s & 63, t = (s >> 6) & 3, ks = s >> 8;
        FragU f = expand_mask(s1m1[(t * 16 + (l & 15)) * 48 + ks * 4 + (l >> 4)]);
        *reinterpret_cast<uint4*>(sfrag + ks * 4096 + t * 1024 + l * 16) = f.u;
    }
    if (tid < C_) {
        float a1 = __fdiv_rn(s1sc[e1 * C_ + tid], denom);
        float a2 = __fdiv_rn(s2sc[e1 * C_ + tid], denom);
        bns[0 * C_ + tid] = a1;
        bns[1 * C_ + tid] = b1[e1 * C_ + tid];
        bns[2 * C_ + tid] = s1bi[e1 * C_ + tid];
        bns[3 * C_ + tid] = a2;
        bns[4 * C_ + tid] = b2[e1 * C_ + tid];
        bns[5 * C_ + tid] = s2bi[e1 * C_ + tid];
        bns[6 * C_ + tid] = __fdiv_rn(1.0f, a2);
    }
    __syncthreads();

#pragma unroll
    for (int os = 0; os < 3; ++os)
#pragma unroll
        for (int t = 0; t < T_; ++t) acc[os][t] = (f32x4)0.0f;
    conv_mfma3(Whif, Wlof, (unsigned)(e1 * 2) * 12u * 24u * 512u, sfrag, acc, wv, lane);

    {   // epi1 r1
#pragma unroll
        for (int os = 0; os < 3; ++os) {
            float v2s[4] = {0.f, 0.f, 0.f, 0.f};
            unsigned pkos = 0;
#pragma unroll
            for (int t = 0; t < T_; ++t) {
                unsigned nb = 0;
#pragma unroll
                for (int r = 0; r < 4; ++r) {
                    int o = wv * 48 + os * 16 + q * 4 + r;
                    int gi = ((t * B_ + b) * C_ + o) * HW_ + p;
                    float y = acc[os][t][r];
                    float h = __fadd_rn(x[gi],
                        __fadd_rn(__fmul_rn(__fadd_rn(y, bns[1 * C_ + o]), bns[0 * C_ + o]),
                                  bns[2 * C_ + o]));
                    v2s[r] = __fadd_rn(v2s[r], __fdiv_rn(__fsub_rn(h, v2s[r]), tau1));
                    if (__fsub_rn(v2s[r], 1.0f) >= 0.0f) { nb |= (1u << r); v2s[r] = 0.f; }
                    acc[os][t][r] = __fmul_rn(h, bns[6 * C_ + o]);
                }
                unsigned nb_hi = (unsigned)__shfl_down((int)nb, 16);
                pkos |= ((nb | (nb_hi << 4)) & 0xFFu) << (8 * t);
            }
            pk[os] = pkos;
        }
    }
    __syncthreads();   // conv1-r1 sfrag reads done

    if ((q & 1) == 0) {   // expand pk -> sfrag
#pragma unroll
        for (int os = 0; os < 3; ++os) {
            int g = wv * 6 + os * 2 + (q >> 1);
            unsigned char* dst = sfrag + (g >> 2) * 4096 + (((g & 3) * 16 + pl) * 16);
#pragma unroll
            for (int t = 0; t < T_; ++t) {
                FragU f = expand_mask((pk[os] >> (8 * t)) & 0xFFu);
                *reinterpret_cast<uint4*>(dst + t * 1024) = f.u;
            }
        }
    }
    __syncthreads();

    conv_mfma3(Whif, Wlof, (unsigned)(e1 * 2 + 1) * 12u * 24u * 512u, sfrag, acc, wv, lane);

    {   // epi2 r1: out = pcomb + wr1*val  (same thread wrote its pcomb slot)
#pragma unroll
        for (int os = 0; os < 3; ++os)
#pragma unroll
            for (int t = 0; t < T_; ++t)
#pragma unroll
                for (int r = 0; r < 4; ++r) {
                    int o = wv * 48 + os * 16 + q * 4 + r;
                    int gi = ((t * B_ + b) * C_ + o) * HW_ + p;
                    float y = acc[os][t][r];
                    float val = __fadd_rn(__fmul_rn(__fadd_rn(y, bns[4 * C_ + o]),
                                                    bns[3 * C_ + o]),
                                          bns[5 * C_ + o]);
                    out[gi] = __fadd_rn(pcomb[(t * C_ + o) * 16 + pl],
                                        __fmul_rn(wr1, val));
                }
    }
}

extern "C" void kernel_launch(void* const* d_in, const int* in_sizes, int n_in,
                              void* d_out, int out_size, void* d_ws, size_t ws_size,
                              hipStream_t stream) {
    const float* x    = (const float*)d_in[0];
    const float* rW   = (const float*)d_in[1];
    const float* rb   = (const float*)d_in[2];
    const float* rbs  = (const float*)d_in[3];
    const float* rbb  = (const float*)d_in[4];
    const float* W1   = (const float*)d_in[5];
    const float* b1   = (const float*)d_in[6];
    const float* s1sc = (const float*)d_in[7];
    const float* s1bi = (const float*)d_in[8];
    const float* W2   = (const float*)d_in[9];
    const float* b2   = (const float*)d_in[10];
    const float* s2sc = (const float*)d_in[11];
    const float* s2bi = (const float*)d_in[12];
    float* out = (float*)d_out;

    // ws layout: Whif (4718592 B) | Wlof (4718592 B) | m (24576 floats)
    unsigned short* Whif = (unsigned short*)d_ws;
    unsigned short* Wlof = Whif + 2359296;
    float* m = (float*)((char*)d_ws + 9437184);

    hipLaunchKernelGGL(k_prep, dim3(384 + B_ * C_), dim3(256), 0, stream,
                       x, W1, W2, Whif, Wlof, m);
    hipLaunchKernelGGL(k_expert, dim3(256), dim3(512), 0, stream,
                       x, m, rW, rb, rbs, rbb, Whif, Wlof,
                       b1, s1sc, s1bi, b2, s2sc, s2bi, out);
}